// Round 17
// baseline (2784.770 us; speedup 1.0000x reference)
//
#include <hip/hip_runtime.h>

#define NV   50000
#define NR   5
#define NT   8
#define CIN  64
#define COUT 64
#define BARY (NR*NT*3)      // 120
#define BK_ELEMS (NR*CIN*NT*COUT)   // 163840 fp16 (320 KB) — L2-resident
#define BM2  64
#define NBLK2 ((NV + BM2 - 1) / BM2)   // 782
#define NCH  80             // chunks: (j 0..7) x (icc 0..9), K=32 each

#define WL_BYTES 262144
#define SIG16_BYTES (NV*CIN*2)                            // 6.4 MB
#define WS_NEED8 (WL_BYTES + 2u*BK_ELEMS + SIG16_BYTES)   // ~7.0 MB

typedef _Float16 f16x8 __attribute__((ext_vector_type(8)));
typedef _Float16 f16x4 __attribute__((ext_vector_type(4)));
typedef float    f32x4 __attribute__((ext_vector_type(4)));

// ---------- K0a: kernel -> fp16, MFMA-FRAGMENT order (v8 layout, unchanged) ----------
// bkf[((icc*8 + m)*64 + lane)*32 + nf*8 + h] = B[col=m*64+nf*16+(lane&15)][ck=(lane>>4)*8+h]
__global__ __launch_bounds__(256) void build_bk8(
    const float* __restrict__ kern, _Float16* __restrict__ bkf)
{
    int e    = blockIdx.x * 256 + threadIdx.x;
    int h    = e & 7;
    int nf   = (e >> 3) & 3;
    int lane = (e >> 5) & 63;
    int m    = (e >> 11) & 7;
    int icc  = e >> 14;
    int d    = nf * 16 + (lane & 15);
    int ck   = (lane >> 4) * 8 + h;
    int c    = (icc & 1) * 32 + ck;
    int i    = icc >> 1;
    bkf[e] = (_Float16)kern[((i * NT + m) * CIN + c) * COUT + d];
}

// ---------- K0b: signal -> fp16 ----------
__global__ __launch_bounds__(256) void build_sig16(
    const float* __restrict__ signal, _Float16* __restrict__ sig16)
{
    int e = blockIdx.x * 256 + threadIdx.x;
    sig16[e] = (_Float16)signal[e];
}

// ---------- main v13 = v8 (round-12, 338us, no-spill) with (512,6): 3 blocks/CU ----------
__global__ __launch_bounds__(512, 6) void geo_mfma13(
    const float* __restrict__ bary_w,
    const int*   __restrict__ bary_idx,
    const _Float16* __restrict__ sig16,
    const _Float16* __restrict__ bkf,
    float* __restrict__ out,
    int*   __restrict__ wl)
{
    // A tile 4 KB, XOR-swizzled: idx ^= g<<4 -> conflict-free R+W (v8-verified)
    __shared__ __align__(16) _Float16 AxsF[4 * BM2 * 8];
    __shared__ float nrm[BM2][NT];
    __shared__ int   besti[BM2];

    const int tid  = threadIdx.x;
    const int lane = tid & 63;
    const int wn   = tid >> 6;         // wave wn owns rotation k=wn
    const int g    = lane >> 4;
    const int l15  = lane & 15;
    const int vbase = blockIdx.x * BM2;

    const int vt = tid >> 3;
    const int cq = tid & 7;
    const int v_mine = vbase + vt;
    const bool v_ok = (v_mine < NV);

    f32x4 acc[4][4];
    {
        f32x4 z = {0.f, 0.f, 0.f, 0.f};
        #pragma unroll
        for (int mf = 0; mf < 4; ++mf)
            #pragma unroll
            for (int nf = 0; nf < 4; ++nf) acc[mf][nf] = z;
    }

    struct Gen { float w0, w1, w2; int i0, i1, i2; };
    auto LOADGEN = [&](int it2) -> Gen {
        Gen gg;
        const int itc = (it2 < NCH) ? it2 : (NCH - 1);
        const int j2   = itc / 10;
        const int icc2 = itc - j2 * 10;
        const int i2   = icc2 >> 1;
        if (v_ok) {
            const int base = v_mine * BARY + (i2 * NT + j2) * 3;
            gg.w0 = bary_w[base + 0];
            gg.w1 = bary_w[base + 1];
            gg.w2 = bary_w[base + 2];
            gg.i0 = bary_idx[base + 0];
            gg.i1 = bary_idx[base + 1];
            gg.i2 = bary_idx[base + 2];
        } else {
            gg.w0 = gg.w1 = gg.w2 = 0.f;
            gg.i0 = gg.i1 = gg.i2 = 0;
        }
        return gg;
    };

    f16x4 sA0, sA1, sA2, sB0, sB1, sB2;
    auto SIGLOAD = [&](const Gen& gg, int it2, f16x4& o0, f16x4& o1, f16x4& o2) {
        const int itc = (it2 < NCH) ? it2 : (NCH - 1);
        const int icc2 = itc - (itc / 10) * 10;
        const int coff = (icc2 & 1) * 32 + cq * 4;
        o0 = *(const f16x4*)(sig16 + gg.i0 * CIN + coff);
        o1 = *(const f16x4*)(sig16 + gg.i1 * CIN + coff);
        o2 = *(const f16x4*)(sig16 + gg.i2 * CIN + coff);
    };

    // B fragments straight from L2 (fragment-ordered, 64 B/lane contiguous)
    auto BFRAG = [&](int it2, f16x8& b0, f16x8& b1, f16x8& b2, f16x8& b3) {
        const int j2   = it2 / 10;
        const int icc2 = it2 - j2 * 10;
        const int m2   = (j2 + wn) & 7;
        const _Float16* src = bkf + ((icc2 * 8 + m2) * 64 + lane) * 32;
        b0 = *(const f16x8*)(src + 0);
        b1 = *(const f16x8*)(src + 8);
        b2 = *(const f16x8*)(src + 16);
        b3 = *(const f16x8*)(src + 24);
    };

    // ---- prologue ----
    Gen g0 = LOADGEN(0);
    Gen g1 = LOADGEN(1);
    SIGLOAD(g0, 0, sA0, sA1, sA2);
    f16x8 bc0, bc1, bc2, bc3, bn0, bn1, bn2, bn3;
    BFRAG(0, bc0, bc1, bc2, bc3);

    const int gw = cq >> 1;
    const int widx = (gw * 512 + vt * 8 + (cq & 1) * 4) ^ (gw << 4);

    #pragma unroll 1
    for (int it = 0; it < NCH; ++it) {
        // ---- phase1: x(it) from regs -> swizzled Axs; refill pipelines ----
        {
            f16x4 hv;
            #pragma unroll
            for (int e = 0; e < 4; ++e) {
                float xf = g0.w0 * (float)sA0[e]
                         + g0.w1 * (float)sA1[e]
                         + g0.w2 * (float)sA2[e];
                hv[e] = (_Float16)xf;
            }
            *(f16x4*)&AxsF[widx] = hv;
        }
        SIGLOAD(g1, it + 1, sB0, sB1, sB2);
        g0 = g1;
        g1 = LOADGEN(it + 2);

        // raw barrier: drain ONLY lgkm (the ds_write); global loads stay in flight
        asm volatile("s_waitcnt lgkmcnt(0)" ::: "memory");
        __builtin_amdgcn_s_barrier();
        asm volatile("" ::: "memory");

        // ---- phase2: issue B(it+1); MFMA from registers + swizzled A ----
        if (it + 1 < NCH) BFRAG(it + 1, bn0, bn1, bn2, bn3);

        f16x8 af[4];
        #pragma unroll
        for (int mf = 0; mf < 4; ++mf) {
            const int row = mf * 16 + l15;
            af[mf] = *(const f16x8*)&AxsF[(g * 512 + row * 8) ^ (g << 4)];
        }

        #pragma unroll
        for (int mf = 0; mf < 4; ++mf) {
            acc[mf][0] = __builtin_amdgcn_mfma_f32_16x16x32_f16(af[mf], bc0, acc[mf][0], 0, 0, 0);
            acc[mf][1] = __builtin_amdgcn_mfma_f32_16x16x32_f16(af[mf], bc1, acc[mf][1], 0, 0, 0);
            acc[mf][2] = __builtin_amdgcn_mfma_f32_16x16x32_f16(af[mf], bc2, acc[mf][2], 0, 0, 0);
            acc[mf][3] = __builtin_amdgcn_mfma_f32_16x16x32_f16(af[mf], bc3, acc[mf][3], 0, 0, 0);
        }

        // raw barrier: afrag reads complete (reg-dep), AxsF safe to overwrite
        asm volatile("" ::: "memory");
        __builtin_amdgcn_s_barrier();
        asm volatile("" ::: "memory");

        bc0 = bn0; bc1 = bn1; bc2 = bn2; bc3 = bn3;
        sA0 = sB0; sA1 = sB1; sA2 = sB2;
    }

    // ---- epilogue: wave wn owns rotation wn; norms per row ----
    #pragma unroll
    for (int mf = 0; mf < 4; ++mf)
        #pragma unroll
        for (int ri = 0; ri < 4; ++ri) {
            float s = 0.f;
            #pragma unroll
            for (int nf = 0; nf < 4; ++nf) {
                float vv = acc[mf][nf][ri];
                s = fmaf(vv, vv, s);
            }
            #pragma unroll
            for (int off = 1; off < 16; off <<= 1)
                s += __shfl_xor(s, off);
            if (l15 == 0) nrm[mf * 16 + g * 4 + ri][wn] = s;
        }
    __syncthreads();

    if (tid < BM2) {
        const int v = vbase + tid;
        float bn = nrm[tid][0];
        float sec = -1e30f;
        int best = 0;
        #pragma unroll
        for (int k = 1; k < NT; ++k) {
            float nv = nrm[tid][k];
            if (nv > bn)       { sec = bn; bn = nv; best = k; }
            else if (nv > sec) { sec = nv; }
        }
        // gap-err sigma ~3.6e-3 -> ~8 sigma (validated rounds 14/16, absmax 0.0156)
        const bool flag = (bn - sec) <= (3.0e-2f + 4e-4f * bn);
        besti[tid] = flag ? -1 : best;
        if (flag && v < NV) { int p = atomicAdd(wl, 1); wl[1 + p] = v; }
    }
    __syncthreads();

    #pragma unroll
    for (int mf = 0; mf < 4; ++mf)
        #pragma unroll
        for (int ri = 0; ri < 4; ++ri) {
            const int row = mf * 16 + g * 4 + ri;
            const int v   = vbase + row;
            const int bsel = (v < NV) ? besti[row] : -1;
            if (bsel == wn) {
                #pragma unroll
                for (int nf = 0; nf < 4; ++nf) {
                    const int d = nf * 16 + l15;
                    out[v * COUT + d] = fmaxf(acc[mf][nf][ri], 0.0f);
                }
            }
        }
}

// ---------- parallel fp64 refine: one BLOCK (4 waves) per vertex ----------
__global__ __launch_bounds__(256) void geo_refine_f64p(
    const float* __restrict__ signal,
    const float* __restrict__ bary_w,
    const int*   __restrict__ bary_idx,
    const float* __restrict__ kern,
    float*       __restrict__ out,
    const int*   __restrict__ wl,
    int nall)
{
    __shared__ __align__(16) float xs[NR][CIN][NT];
    __shared__ double part[4][NT][COUT];
    __shared__ double convl[NT][COUT];
    __shared__ double nks[NT];
    __shared__ int bestS;

    const int tid  = threadIdx.x;
    const int wave = tid >> 6;
    const int lane = tid & 63;
    const int count = wl ? wl[0] : nall;

    for (int w = blockIdx.x; w < count; w += gridDim.x) {
        const int v = wl ? wl[1 + w] : w;

        for (int ij = wave; ij < NR * NT; ij += 4) {
            const int i = ij >> 3, j = ij & 7;
            const int base = v * BARY + ij * 3;
            const float w0 = bary_w[base], w1 = bary_w[base+1], w2 = bary_w[base+2];
            const int   i0 = bary_idx[base], i1 = bary_idx[base+1], i2 = bary_idx[base+2];
            xs[i][lane][j] = w0 * signal[i0*CIN + lane]
                           + w1 * signal[i1*CIN + lane]
                           + w2 * signal[i2*CIN + lane];
        }
        __syncthreads();

        double acc[NT];
        #pragma unroll
        for (int k = 0; k < NT; ++k) acc[k] = 0.0;

        for (int r = wave * 80; r < wave * 80 + 80; ++r) {
            const int i = r >> 6, c = r & 63;
            const float4 xa = *reinterpret_cast<const float4*>(&xs[i][c][0]);
            const float4 xb = *reinterpret_cast<const float4*>(&xs[i][c][4]);
            const double x8[NT] = {(double)xa.x, (double)xa.y, (double)xa.z, (double)xa.w,
                                   (double)xb.x, (double)xb.y, (double)xb.z, (double)xb.w};
            #pragma unroll
            for (int mm = 0; mm < NT; ++mm) {
                const double kv = (double)kern[((i * NT + mm) * CIN + c) * COUT + lane];
                #pragma unroll
                for (int k = 0; k < NT; ++k)
                    acc[k] = fma(x8[(mm - k + NT) & (NT - 1)], kv, acc[k]);
            }
        }
        #pragma unroll
        for (int k = 0; k < NT; ++k) part[wave][k][lane] = acc[k];
        __syncthreads();

        for (int kd = tid; kd < NT * COUT; kd += 256) {
            const int k = kd >> 6, d = kd & 63;
            convl[k][d] = ((part[0][k][d] + part[1][k][d])
                         + (part[2][k][d] + part[3][k][d]));
        }
        __syncthreads();

        for (int k = wave; k < NT; k += 4) {
            double n = convl[k][lane] * convl[k][lane];
            #pragma unroll
            for (int off = 32; off >= 1; off >>= 1) n += __shfl_xor(n, off);
            if (lane == 0) nks[k] = n;
        }
        __syncthreads();

        if (tid == 0) {
            int best = 0; double bn = nks[0];
            #pragma unroll
            for (int k = 1; k < NT; ++k)
                if (nks[k] > bn) { bn = nks[k]; best = k; }
            bestS = best;
        }
        __syncthreads();

        if (tid < COUT) out[v * COUT + tid] = fmaxf((float)convl[bestS][tid], 0.0f);
        __syncthreads();
    }
}

extern "C" void kernel_launch(void* const* d_in, const int* in_sizes, int n_in,
                              void* d_out, int out_size, void* d_ws, size_t ws_size,
                              hipStream_t stream) {
    const float* signal   = (const float*)d_in[0];
    const float* bary_w   = (const float*)d_in[1];
    const int*   bary_idx = (const int*)d_in[2];
    const float* kern     = (const float*)d_in[3];
    float* out = (float*)d_out;

    if (ws_size >= (size_t)WS_NEED8) {
        int* wl = (int*)d_ws;
        _Float16* bkf   = (_Float16*)((char*)d_ws + WL_BYTES);
        _Float16* sig16 = (_Float16*)((char*)d_ws + WL_BYTES + 2u * BK_ELEMS);
        hipMemsetAsync(wl, 0, sizeof(int), stream);
        build_bk8<<<dim3(BK_ELEMS / 256), dim3(256), 0, stream>>>(kern, bkf);
        build_sig16<<<dim3(NV * CIN / 256), dim3(256), 0, stream>>>(signal, sig16);
        geo_mfma13<<<dim3(NBLK2), dim3(512), 0, stream>>>(
            bary_w, bary_idx, sig16, bkf, out, wl);
        geo_refine_f64p<<<dim3(1024), dim3(256), 0, stream>>>(
            signal, bary_w, bary_idx, kern, out, wl, 0);
    } else {
        geo_refine_f64p<<<dim3(1024), dim3(256), 0, stream>>>(
            signal, bary_w, bary_idx, kern, out, nullptr, NV);
    }
}

// Round 18
// 429.446 us; speedup vs baseline: 6.4846x; 6.4846x over previous
//
#include <hip/hip_runtime.h>

#define NV   50000
#define NR   5
#define NT   8
#define CIN  64
#define COUT 64
#define BARY (NR*NT*3)      // 120
#define BK_ELEMS (NR*CIN*NT*COUT)   // 163840 fp16 (320 KB) — L2-resident
#define BM2  64
#define NBLK2 ((NV + BM2 - 1) / BM2)   // 782
#define NCH  80             // chunks: (j 0..7) x (icc 0..9), K=32 each

#define WL_BYTES 262144
#define SIG16_BYTES (NV*CIN*2)                            // 6.4 MB
#define WS_NEED8 (WL_BYTES + 2u*BK_ELEMS + SIG16_BYTES)   // ~7.0 MB

typedef _Float16 f16x8 __attribute__((ext_vector_type(8)));
typedef _Float16 f16x4 __attribute__((ext_vector_type(4)));
typedef float    f32x4 __attribute__((ext_vector_type(4)));

// ---------- K0a: kernel -> fp16 ws with the LDS read-swizzle PRE-BAKED ----------
// (verified correct in round 16.) Staging copies bk linearly into Blds; the
// MFMA read uses 16B-granule u = gi ^ ((gi>>3)&7) (involution), so sigma is
// baked here: for granule u, source granule gi: col = gi>>2, gq = gi&3.
__global__ __launch_bounds__(256) void build_bk12(
    const float* __restrict__ kern, _Float16* __restrict__ bk)
{
    int e   = blockIdx.x * 256 + threadIdx.x;
    int h   = e & 7;
    int u   = (e >> 3) & 2047;
    int icc = e >> 14;
    int gi  = u ^ ((u >> 3) & 7);     // involution (bits 3-5 untouched)
    int col = gi >> 2;
    int gq  = gi & 3;
    int i   = icc >> 1;
    int c   = (icc & 1) * 32 + gq * 8 + h;
    int m   = col >> 6;
    int d   = col & 63;
    bk[e] = (_Float16)kern[((i * NT + m) * CIN + c) * COUT + d];
}

// ---------- K0b: signal -> fp16 ----------
__global__ __launch_bounds__(256) void build_sig16(
    const float* __restrict__ signal, _Float16* __restrict__ sig16)
{
    int e = blockIdx.x * 256 + threadIdx.x;
    sig16[e] = (_Float16)signal[e];
}

// ---------- main v14 = v7 (323us, no-spill) + A-XOR-swizzle (v8-proven)
// ----------            + baked B-swizzle (v12-proven). __syncthreads kept.
__global__ __launch_bounds__(512, 4) void geo_mfma14(
    const float* __restrict__ bary_w,
    const int*   __restrict__ bary_idx,
    const _Float16* __restrict__ sig16,
    const _Float16* __restrict__ bk,
    float* __restrict__ out,
    int*   __restrict__ wl)
{
    __shared__ __align__(16) _Float16 Blds[2][16384];   // 2 x 32 KB
    __shared__ __align__(16) _Float16 AxsF[4 * BM2 * 8];// 4 KB, XOR-swizzled
    __shared__ float nrm[BM2][NT];                      // 2 KB
    __shared__ int   besti[BM2];

    const int tid  = threadIdx.x;
    const int lane = tid & 63;
    const int wn   = tid >> 6;         // wave wn owns rotation k=wn
    const int g    = lane >> 4;
    const int l15  = lane & 15;
    const int vbase = blockIdx.x * BM2;

    // A-staging mapping: thread -> (vertex vt, ck-quad cq); 4 channels each
    const int vt = tid >> 3;
    const int cq = tid & 7;
    const int v_mine = vbase + vt;
    const bool v_ok = (v_mine < NV);

    f32x4 acc[4][4];
    {
        f32x4 z = {0.f, 0.f, 0.f, 0.f};
        #pragma unroll
        for (int mf = 0; mf < 4; ++mf)
            #pragma unroll
            for (int nf = 0; nf < 4; ++nf) acc[mf][nf] = z;
    }

    struct Gen { float w0, w1, w2; int i0, i1, i2; };
    auto LOADGEN = [&](int it2) -> Gen {
        Gen gg;
        const int itc = (it2 < NCH) ? it2 : (NCH - 1);
        const int j2   = itc / 10;
        const int icc2 = itc - j2 * 10;
        const int i2   = icc2 >> 1;
        if (v_ok) {
            const int base = v_mine * BARY + (i2 * NT + j2) * 3;
            gg.w0 = bary_w[base + 0];
            gg.w1 = bary_w[base + 1];
            gg.w2 = bary_w[base + 2];
            gg.i0 = bary_idx[base + 0];
            gg.i1 = bary_idx[base + 1];
            gg.i2 = bary_idx[base + 2];
        } else {
            gg.w0 = gg.w1 = gg.w2 = 0.f;
            gg.i0 = gg.i1 = gg.i2 = 0;
        }
        return gg;
    };

    f16x4 sA0, sA1, sA2, sB0, sB1, sB2;
    auto SIGLOAD = [&](const Gen& gg, int it2, f16x4& o0, f16x4& o1, f16x4& o2) {
        const int itc = (it2 < NCH) ? it2 : (NCH - 1);
        const int icc2 = itc - (itc / 10) * 10;
        const int coff = (icc2 & 1) * 32 + cq * 4;
        o0 = *(const f16x4*)(sig16 + gg.i0 * CIN + coff);
        o1 = *(const f16x4*)(sig16 + gg.i1 * CIN + coff);
        o2 = *(const f16x4*)(sig16 + gg.i2 * CIN + coff);
    };

    // B chunk reg-staging (linear copy; permutation pre-baked in ws)
    f16x8 breg0, breg1, breg2, breg3;
    auto BLOADR = [&](int icc2) {
        const _Float16* src = bk + icc2 * 16384 + wn * 2048 + lane * 8;
        breg0 = *(const f16x8*)(src + 0 * 512);
        breg1 = *(const f16x8*)(src + 1 * 512);
        breg2 = *(const f16x8*)(src + 2 * 512);
        breg3 = *(const f16x8*)(src + 3 * 512);
    };
    auto BWRITE = [&](int b) {
        _Float16* dst = &Blds[b][wn * 2048 + lane * 8];
        *(f16x8*)(dst + 0 * 512) = breg0;
        *(f16x8*)(dst + 1 * 512) = breg1;
        *(f16x8*)(dst + 2 * 512) = breg2;
        *(f16x8*)(dst + 3 * 512) = breg3;
    };

    const int gw   = cq >> 1;
    const int widx = (gw * 512 + vt * 8 + (cq & 1) * 4) ^ (gw << 4);

    // ---- prologue ----
    Gen g0 = LOADGEN(0);
    Gen g1 = LOADGEN(1);
    SIGLOAD(g0, 0, sA0, sA1, sA2);
    BLOADR(0);
    BWRITE(0);
    __syncthreads();

    int cur = 0;
    #pragma unroll 1
    for (int it = 0; it < NCH; ++it) {
        const int j = it / 10;
        const int m = (j + wn) & 7;

        // ---- phase1: x(it) from regs -> swizzled AxsF; issue next sig/bary ----
        {
            f16x4 hv;
            #pragma unroll
            for (int e = 0; e < 4; ++e) {
                float xf = g0.w0 * (float)sA0[e]
                         + g0.w1 * (float)sA1[e]
                         + g0.w2 * (float)sA2[e];
                hv[e] = (_Float16)xf;
            }
            *(f16x4*)&AxsF[widx] = hv;
        }
        SIGLOAD(g1, it + 1, sB0, sB1, sB2);
        Gen g2 = LOADGEN(it + 2);
        __syncthreads();   // bar1: AxsF ready

        // ---- phase2: issue B(it+1) loads early; MFMA from LDS; write B ----
        const int iccn = (it + 1 < NCH) ? ((it + 1) - ((it + 1) / 10) * 10) : 0;
        if (it + 1 < NCH) BLOADR(iccn);

        f16x8 afrag[4];
        #pragma unroll
        for (int mf = 0; mf < 4; ++mf) {
            const int row = mf * 16 + l15;
            afrag[mf] = *(const f16x8*)&AxsF[(g * 512 + row * 8) ^ (g << 4)];
        }

        #pragma unroll
        for (int nf = 0; nf < 4; ++nf) {
            const int col = m * 64 + nf * 16 + l15;
            const int gi  = col * 4 + g;
            const int u   = gi ^ ((gi >> 3) & 7);   // matches baked sigma
            const f16x8 bfrag = *(const f16x8*)&Blds[cur][u * 8];
            #pragma unroll
            for (int mf = 0; mf < 4; ++mf)
                acc[mf][nf] = __builtin_amdgcn_mfma_f32_16x16x32_f16(
                    afrag[mf], bfrag, acc[mf][nf], 0, 0, 0);
        }

        if (it + 1 < NCH) BWRITE(cur ^ 1);   // waits vmcnt on breg*
        __syncthreads();   // bar2: B(it+1) visible; AxsF free

        // rotate pipeline (v7-proven inventory)
        g0 = g1; g1 = g2;
        sA0 = sB0; sA1 = sB1; sA2 = sB2;
        cur ^= 1;
    }

    // ---- epilogue: wave wn owns rotation wn; norms per row ----
    #pragma unroll
    for (int mf = 0; mf < 4; ++mf)
        #pragma unroll
        for (int ri = 0; ri < 4; ++ri) {
            float s = 0.f;
            #pragma unroll
            for (int nf = 0; nf < 4; ++nf) {
                float vv = acc[mf][nf][ri];
                s = fmaf(vv, vv, s);
            }
            #pragma unroll
            for (int off = 1; off < 16; off <<= 1)
                s += __shfl_xor(s, off);
            if (l15 == 0) nrm[mf * 16 + g * 4 + ri][wn] = s;
        }
    __syncthreads();

    if (tid < BM2) {
        const int v = vbase + tid;
        float bn = nrm[tid][0];
        float sec = -1e30f;
        int best = 0;
        #pragma unroll
        for (int k = 1; k < NT; ++k) {
            float nv = nrm[tid][k];
            if (nv > bn)       { sec = bn; bn = nv; best = k; }
            else if (nv > sec) { sec = nv; }
        }
        // gap-err sigma ~3.6e-3 -> ~8 sigma (validated rounds 14-17)
        const bool flag = (bn - sec) <= (3.0e-2f + 4e-4f * bn);
        besti[tid] = flag ? -1 : best;
        if (flag && v < NV) { int p = atomicAdd(wl, 1); wl[1 + p] = v; }
    }
    __syncthreads();

    #pragma unroll
    for (int mf = 0; mf < 4; ++mf)
        #pragma unroll
        for (int ri = 0; ri < 4; ++ri) {
            const int row = mf * 16 + g * 4 + ri;
            const int v   = vbase + row;
            const int bsel = (v < NV) ? besti[row] : -1;
            if (bsel == wn) {
                #pragma unroll
                for (int nf = 0; nf < 4; ++nf) {
                    const int d = nf * 16 + l15;
                    out[v * COUT + d] = fmaxf(acc[mf][nf][ri], 0.0f);
                }
            }
        }
}

// ---------- parallel fp64 refine: one BLOCK (4 waves) per vertex ----------
__global__ __launch_bounds__(256) void geo_refine_f64p(
    const float* __restrict__ signal,
    const float* __restrict__ bary_w,
    const int*   __restrict__ bary_idx,
    const float* __restrict__ kern,
    float*       __restrict__ out,
    const int*   __restrict__ wl,
    int nall)
{
    __shared__ __align__(16) float xs[NR][CIN][NT];
    __shared__ double part[4][NT][COUT];
    __shared__ double convl[NT][COUT];
    __shared__ double nks[NT];
    __shared__ int bestS;

    const int tid  = threadIdx.x;
    const int wave = tid >> 6;
    const int lane = tid & 63;
    const int count = wl ? wl[0] : nall;

    for (int w = blockIdx.x; w < count; w += gridDim.x) {
        const int v = wl ? wl[1 + w] : w;

        for (int ij = wave; ij < NR * NT; ij += 4) {
            const int i = ij >> 3, j = ij & 7;
            const int base = v * BARY + ij * 3;
            const float w0 = bary_w[base], w1 = bary_w[base+1], w2 = bary_w[base+2];
            const int   i0 = bary_idx[base], i1 = bary_idx[base+1], i2 = bary_idx[base+2];
            xs[i][lane][j] = w0 * signal[i0*CIN + lane]
                           + w1 * signal[i1*CIN + lane]
                           + w2 * signal[i2*CIN + lane];
        }
        __syncthreads();

        double acc[NT];
        #pragma unroll
        for (int k = 0; k < NT; ++k) acc[k] = 0.0;

        for (int r = wave * 80; r < wave * 80 + 80; ++r) {
            const int i = r >> 6, c = r & 63;
            const float4 xa = *reinterpret_cast<const float4*>(&xs[i][c][0]);
            const float4 xb = *reinterpret_cast<const float4*>(&xs[i][c][4]);
            const double x8[NT] = {(double)xa.x, (double)xa.y, (double)xa.z, (double)xa.w,
                                   (double)xb.x, (double)xb.y, (double)xb.z, (double)xb.w};
            #pragma unroll
            for (int mm = 0; mm < NT; ++mm) {
                const double kv = (double)kern[((i * NT + mm) * CIN + c) * COUT + lane];
                #pragma unroll
                for (int k = 0; k < NT; ++k)
                    acc[k] = fma(x8[(mm - k + NT) & (NT - 1)], kv, acc[k]);
            }
        }
        #pragma unroll
        for (int k = 0; k < NT; ++k) part[wave][k][lane] = acc[k];
        __syncthreads();

        for (int kd = tid; kd < NT * COUT; kd += 256) {
            const int k = kd >> 6, d = kd & 63;
            convl[k][d] = ((part[0][k][d] + part[1][k][d])
                         + (part[2][k][d] + part[3][k][d]));
        }
        __syncthreads();

        for (int k = wave; k < NT; k += 4) {
            double n = convl[k][lane] * convl[k][lane];
            #pragma unroll
            for (int off = 32; off >= 1; off >>= 1) n += __shfl_xor(n, off);
            if (lane == 0) nks[k] = n;
        }
        __syncthreads();

        if (tid == 0) {
            int best = 0; double bn = nks[0];
            #pragma unroll
            for (int k = 1; k < NT; ++k)
                if (nks[k] > bn) { bn = nks[k]; best = k; }
            bestS = best;
        }
        __syncthreads();

        if (tid < COUT) out[v * COUT + tid] = fmaxf((float)convl[bestS][tid], 0.0f);
        __syncthreads();
    }
}

extern "C" void kernel_launch(void* const* d_in, const int* in_sizes, int n_in,
                              void* d_out, int out_size, void* d_ws, size_t ws_size,
                              hipStream_t stream) {
    const float* signal   = (const float*)d_in[0];
    const float* bary_w   = (const float*)d_in[1];
    const int*   bary_idx = (const int*)d_in[2];
    const float* kern     = (const float*)d_in[3];
    float* out = (float*)d_out;

    if (ws_size >= (size_t)WS_NEED8) {
        int* wl = (int*)d_ws;
        _Float16* bk    = (_Float16*)((char*)d_ws + WL_BYTES);
        _Float16* sig16 = (_Float16*)((char*)d_ws + WL_BYTES + 2u * BK_ELEMS);
        hipMemsetAsync(wl, 0, sizeof(int), stream);
        build_bk12<<<dim3(BK_ELEMS / 256), dim3(256), 0, stream>>>(kern, bk);
        build_sig16<<<dim3(NV * CIN / 256), dim3(256), 0, stream>>>(signal, sig16);
        geo_mfma14<<<dim3(NBLK2), dim3(512), 0, stream>>>(
            bary_w, bary_idx, sig16, bk, out, wl);
        geo_refine_f64p<<<dim3(1024), dim3(256), 0, stream>>>(
            signal, bary_w, bary_idx, kern, out, wl, 0);
    } else {
        geo_refine_f64p<<<dim3(1024), dim3(256), 0, stream>>>(
            signal, bary_w, bary_idx, kern, out, nullptr, NV);
    }
}